// Round 3
// baseline (552.464 us; speedup 1.0000x reference)
//
#include <hip/hip_runtime.h>

// Problem dims (fixed by setup_inputs): x[4,2048,4096] f32, W[4096,4096] f32,
// lora_A[16,4096], lora_B[4096,16], sigma[16]. out[4,2048,4096] f32.
// out = x @ (W + SCALING * (B*diag(sigma_masked)) @ A)^T
#define D_DIM 4096
#define R_DIM 16
#define SCALING_F 1.0f          // 16.0/16
#define THRESH 0.01f

typedef __attribute__((ext_vector_type(8))) short short8;     // 8 bf16
typedef __attribute__((ext_vector_type(16))) float floatx16;  // 32x32 MFMA C/D

__device__ __forceinline__ unsigned int f2bf(float f) {
  union { float f; unsigned int u; } v; v.f = f;
  unsigned int u = v.u;
  u += 0x7FFFu + ((u >> 16) & 1u);   // round-to-nearest-even
  return u >> 16;
}

// ---------- fused prep: x f32->bf16 AND W_eff build, one launch ----------
__global__ __launch_bounds__(256) void prep_kernel(
    const float* __restrict__ x, unsigned int* __restrict__ xb, int n8,
    int nxblocks,
    const float* __restrict__ W, const float* __restrict__ lA,
    const float* __restrict__ lB, const float* __restrict__ sigma,
    unsigned int* __restrict__ wb) {
  __shared__ float Bs[R_DIM];
  int b = blockIdx.x;
  if (b < nxblocks) {
    int idx = b * 256 + threadIdx.x;
    if (idx >= n8) return;
    const float4* xp = (const float4*)x;
    float4 v0 = xp[2 * idx];
    float4 v1 = xp[2 * idx + 1];
    uint4 o;
    o.x = f2bf(v0.x) | (f2bf(v0.y) << 16);
    o.y = f2bf(v0.z) | (f2bf(v0.w) << 16);
    o.z = f2bf(v1.x) | (f2bf(v1.y) << 16);
    o.w = f2bf(v1.z) | (f2bf(v1.w) << 16);
    ((uint4*)xb)[idx] = o;
  } else {
    int idx = (b - nxblocks) * 256 + threadIdx.x;  // float4 index
    int o  = idx >> 10;                             // row (uniform per block)
    int dq = idx & 1023;
    if (threadIdx.x < R_DIM) {
      float s = sigma[threadIdx.x];
      s = (fabsf(s) >= THRESH) ? s : 0.0f;
      Bs[threadIdx.x] = lB[o * R_DIM + threadIdx.x] * s * SCALING_F;
    }
    __syncthreads();
    float4 acc = ((const float4*)W)[idx];
#pragma unroll
    for (int r = 0; r < R_DIM; ++r) {
      float bb = Bs[r];
      float4 a = ((const float4*)(lA + (size_t)r * D_DIM))[dq];
      acc.x += bb * a.x; acc.y += bb * a.y; acc.z += bb * a.z; acc.w += bb * a.w;
    }
    uint2 p;
    p.x = f2bf(acc.x) | (f2bf(acc.y) << 16);
    p.y = f2bf(acc.z) | (f2bf(acc.w) << 16);
    ((uint2*)wb)[idx] = p;
  }
}

// =====================================================================
// GEMM: C[M,N] = A[M,K] * B[N,K]^T, bf16 in, f32 out.
// 256x256 tile, BK=64, 8 waves (2M x 4N), 512 threads, 128 KiB LDS.
// R1-proven 8-phase schedule; MFMA shape switched to 32x32x16 (8 MFMA per
// phase instead of 16x 16x16x32 — half the issue slots, +15% pipe ceiling).
//
// LDS map (bytes): A-buf0 @0, A-buf1 @32768, B-buf0 @65536, B-buf1 @98304.
// Tile = 256 rows x 64 bf16 = 32 KB, row stride 128 B. Row permutation:
//   A: LDS row = qm*128 + wm*64 + i  (holds global row wm*128+qm*64+i)
//   B: LDS row = qn*128 + wn*32 + i  (holds global col wn*64+qn*32+i)
// 16B-granule XOR swizzle: slot s holds kgroup s^(row&7); inverse applied
// to GLOBAL source addr (linear LDS dest), same XOR on ds_read.
// 32x32x16 operand: lane&31 = row/col, lane>>5 = k-half (8 bf16 = kgroup
// 2s+(lane>>5)); read slot = (2s+kh)^(row&7). Each 8-lane b128 subphase
// covers rows r..r+7 -> 8 distinct slots -> conflict-free.
//
// Quadrant order per tile: c1=(0,0) c2=(0,1) c3=(1,1) c4=(1,0); A-frags
// loaded at c1/c3 (reused next phase), B at c1/c2/c4. Staging rotation and
// vmcnt(4)-at-P4/P8 discipline identical to the verified R1 kernel.
// =====================================================================

__device__ __forceinline__ void stage16(const void* g, void* l) {
  __builtin_amdgcn_global_load_lds(
      (const __attribute__((address_space(1))) void*)g,
      (__attribute__((address_space(3))) void*)l, 16, 0, 0);
}

#define FENCE() __builtin_amdgcn_sched_barrier(0)

#define SYNC_MID()                                      \
  FENCE();                                              \
  __builtin_amdgcn_s_barrier();                         \
  asm volatile("s_waitcnt lgkmcnt(0)" ::: "memory");    \
  FENCE()

#define SYNC_END()                                      \
  FENCE();                                              \
  __builtin_amdgcn_s_barrier();                         \
  FENCE()

#define SYNC_END_VM()                                   \
  FENCE();                                              \
  asm volatile("s_waitcnt vmcnt(4)" ::: "memory");      \
  __builtin_amdgcn_s_barrier();                         \
  FENCE()

// A fragments for quadrant QM: aF[i2][s], i2 = 32-row group, s = k-step.
#define LOADA32(BUF, QM)                                                       \
  _Pragma("unroll") for (int s = 0; s < 4; ++s) {                              \
    aF[0][s] = *(const short8*)(aRdB + (BUF)*32768 + (QM)*16384 +              \
                                (((2*s + kh) ^ r7) << 4));                     \
    aF[1][s] = *(const short8*)(aRdB + (BUF)*32768 + (QM)*16384 + 4096 +       \
                                (((2*s + kh) ^ r7) << 4));                     \
  }

#define LOADB32(BUF, QN)                                                       \
  _Pragma("unroll") for (int s = 0; s < 4; ++s)                                \
    bF[s] = *(const short8*)(bRdB + (BUF)*32768 + (QN)*16384 +                 \
                             (((2*s + kh) ^ r7) << 4));

#define MFMAQ32(QM, QN)                                                        \
  __builtin_amdgcn_s_setprio(1);                                               \
  _Pragma("unroll") for (int s = 0; s < 4; ++s) {                              \
    acc[QM][QN][0] = __builtin_amdgcn_mfma_f32_32x32x16_bf16(                  \
        aF[0][s], bF[s], acc[QM][QN][0], 0, 0, 0);                             \
    acc[QM][QN][1] = __builtin_amdgcn_mfma_f32_32x32x16_bf16(                  \
        aF[1][s], bF[s], acc[QM][QN][1], 0, 0, 0);                             \
  }                                                                            \
  __builtin_amdgcn_s_setprio(0);                                               \
  FENCE()

__global__ __launch_bounds__(512, 2) void gemm_bt_kernel(
    const unsigned short* __restrict__ A,   // x bf16 [M, K]
    const unsigned short* __restrict__ B,   // W_eff bf16 [N, K]
    float* __restrict__ C, int M) {
  __shared__ __align__(16) char lds[131072];

  const int tid  = threadIdx.x;
  const int lane = tid & 63;
  const int wave = tid >> 6;      // 0..7
  const int wm   = wave >> 2;     // 0..1 (128 rows each)
  const int wn   = wave & 3;      // 0..3 (64 cols each)
  const int l31  = lane & 31;
  const int kh   = lane >> 5;     // k-half selector
  const int r7   = l31 & 7;

  // XCD-bijective block swizzle (gridDim.x % 8 == 0 here: 512 blocks).
  const int bid = blockIdx.x;
  const int cpx = gridDim.x >> 3;
  const int swz = (bid & 7) * cpx + (bid >> 3);
  const int m0 = (swz >> 4) << 8;           // 16 n-tiles (D_DIM/256)
  const int n0 = (swz & 15) << 8;

  // ---- staging source bases (per thread) ----
  const int rr8  = tid >> 3;                               // 0..63
  const int kgsw = (tid & 7) ^ (rr8 & 7);
  const char* aSrc = (const char*)A + ((size_t)(m0 + rr8) << 13) + (kgsw << 4);
  const int nrow = (rr8 & 31) | ((rr8 & 32) << 1);
  const char* bSrc = (const char*)B + ((size_t)(n0 + nrow) << 13) + (kgsw << 4);
  char* ldsW = lds + wave * 1024;           // wave-uniform dest base

  // ---- fragment read bases (per lane) ----
  const char* aRdB = lds + wm * 8192 + l31 * 128;
  const char* bRdB = lds + 65536 + wn * 4096 + l31 * 128;

  short8 aF[2][4], bF[4];
  floatx16 acc[2][2][2] = {};     // [qm][qn][i2]

  // ---- prologue: tile0 (all 4 halves) -> buf0, A0(1)+B1(1) -> buf1 ----
  stage16(aSrc,                     ldsW + 0);        // A0(0)
  stage16(aSrc + (128 << 13),       ldsW + 8192);
  stage16(aSrc + (64 << 13),        ldsW + 16384);    // A1(0)
  stage16(aSrc + (192 << 13),       ldsW + 24576);
  stage16(bSrc,                     ldsW + 65536);    // B0(0)
  stage16(bSrc + (128 << 13),       ldsW + 73728);
  stage16(bSrc + (32 << 13),        ldsW + 81920);    // B1(0)
  stage16(bSrc + (160 << 13),       ldsW + 90112);
  stage16(aSrc + 128,               ldsW + 32768);    // A0(1) -> buf1
  stage16(aSrc + (128 << 13) + 128, ldsW + 40960);
  stage16(bSrc + (32 << 13) + 128,  ldsW + 114688);   // B1(1) -> buf1
  stage16(bSrc + (160 << 13) + 128, ldsW + 122880);
  FENCE();
  asm volatile("s_waitcnt vmcnt(4)" ::: "memory");    // tile0 landed
  __builtin_amdgcn_s_barrier();
  FENCE();

  int kb = 0;                                // f*256 bytes (2 tiles/frame)
#pragma unroll 1
  for (int f = 0; f < 32; ++f) {             // 64 K-tiles, 2 per frame
    const int k1 = (kb + 128) & 8191;        // ktile 2f+1 byte offset
    const int k2 = (kb + 256) & 8191;        // ktile 2f+2 (wraps at tail)
    const int k3 = (kb + 384) & 8191;        // ktile 2f+3 (wraps at tail)

    // P1: tile 2f c1=(0,0) from buf0; stage A1(2f+1)->buf1
    LOADA32(0, 0) LOADB32(0, 0)
    stage16(aSrc + (64 << 13) + k1,  ldsW + 49152);
    stage16(aSrc + (192 << 13) + k1, ldsW + 57344);
    SYNC_MID();
    MFMAQ32(0, 0);
    SYNC_END();

    // P2: c2=(0,1) (A reused); stage B0(2f+1)->buf1
    LOADB32(0, 1)
    stage16(bSrc + k1,               ldsW + 98304);
    stage16(bSrc + (128 << 13) + k1, ldsW + 106496);
    SYNC_MID();
    MFMAQ32(0, 1);
    SYNC_END();

    // P3: c3=(1,1) (B reused); stage A0(2f+2)->buf0 (A0 retired after P1)
    LOADA32(0, 1)
    stage16(aSrc + k2,               ldsW + 0);
    stage16(aSrc + (128 << 13) + k2, ldsW + 8192);
    SYNC_MID();
    MFMAQ32(1, 1);
    SYNC_END();

    // P4: c4=(1,0) (A reused); stage B1(2f+2)->buf0 (B1 retired after P2)
    LOADB32(0, 0)
    stage16(bSrc + (32 << 13) + k2,  ldsW + 81920);
    stage16(bSrc + (160 << 13) + k2, ldsW + 90112);
    SYNC_MID();
    MFMAQ32(1, 0);
    SYNC_END_VM();   // vmcnt(4): everything except P3/P4 stages landed

    // P5: tile 2f+1 c1=(0,0) from buf1; stage A1(2f+2)->buf0
    LOADA32(1, 0) LOADB32(1, 0)
    stage16(aSrc + (64 << 13) + k2,  ldsW + 16384);
    stage16(aSrc + (192 << 13) + k2, ldsW + 24576);
    SYNC_MID();
    MFMAQ32(0, 0);
    SYNC_END();

    // P6: c2=(0,1); stage B0(2f+2)->buf0
    LOADB32(1, 1)
    stage16(bSrc + k2,               ldsW + 65536);
    stage16(bSrc + (128 << 13) + k2, ldsW + 73728);
    SYNC_MID();
    MFMAQ32(0, 1);
    SYNC_END();

    // P7: c3=(1,1); stage A0(2f+3)->buf1
    LOADA32(1, 1)
    stage16(aSrc + k3,               ldsW + 32768);
    stage16(aSrc + (128 << 13) + k3, ldsW + 40960);
    SYNC_MID();
    MFMAQ32(1, 1);
    SYNC_END();

    // P8: c4=(1,0); stage B1(2f+3)->buf1
    LOADB32(1, 0)
    stage16(bSrc + (32 << 13) + k3,  ldsW + 114688);
    stage16(bSrc + (160 << 13) + k3, ldsW + 122880);
    SYNC_MID();
    MFMAQ32(1, 0);
    SYNC_END_VM();

    kb += 256;
  }

  // ---- epilogue: 32x32 C/D layout: col=lane&31,
  //      row=(reg&3)+8*(reg>>2)+4*(lane>>5), reg=g*4+rr ----
#pragma unroll
  for (int qm = 0; qm < 2; ++qm)
#pragma unroll
    for (int i2 = 0; i2 < 2; ++i2)
#pragma unroll
      for (int g = 0; g < 4; ++g)
#pragma unroll
        for (int rr = 0; rr < 4; ++rr) {
          const int row = m0 + wm * 128 + qm * 64 + i2 * 32 +
                          g * 8 + kh * 4 + rr;
          float* cp = C + (size_t)row * D_DIM + n0 + wn * 64 + l31;
          cp[0]  = acc[qm][0][i2][g * 4 + rr];
          cp[32] = acc[qm][1][i2][g * 4 + rr];
        }
}

extern "C" void kernel_launch(void* const* d_in, const int* in_sizes, int n_in,
                              void* d_out, int out_size, void* d_ws, size_t ws_size,
                              hipStream_t stream) {
  const float* x     = (const float*)d_in[0];  // [M, 4096], M = 8192
  const float* W     = (const float*)d_in[1];  // [4096, 4096]
  const float* lA    = (const float*)d_in[2];  // [16, 4096]
  const float* lB    = (const float*)d_in[3];  // [4096, 16]
  const float* sigma = (const float*)d_in[4];  // [16]
  float* out = (float*)d_out;

  const int M = in_sizes[0] / D_DIM;           // 8192
  // Workspace layout: x_bf16 (M*4096*2 = 64 MB) then W_eff bf16 (32 MB).
  unsigned int* xb = (unsigned int*)d_ws;
  unsigned int* wb = (unsigned int*)((char*)d_ws + (size_t)M * D_DIM * 2);

  const int n8 = in_sizes[0] / 8;              // x octets
  const int nxblocks = (n8 + 255) / 256;       // 16384
  const int nwblocks = (D_DIM * D_DIM / 4) / 256;  // 16384
  prep_kernel<<<nxblocks + nwblocks, 256, 0, stream>>>(
      x, xb, n8, nxblocks, W, lA, lB, sigma, wb);

  const int nblocks = (M / 256) * (D_DIM / 256);   // 32*16 = 512
  gemm_bt_kernel<<<nblocks, 512, 0, stream>>>(
      (const unsigned short*)xb, (const unsigned short*)wb, out, M);
}

// Round 4
// 532.564 us; speedup vs baseline: 1.0374x; 1.0374x over previous
//
#include <hip/hip_runtime.h>

// Problem dims (fixed by setup_inputs): x[4,2048,4096] f32, W[4096,4096] f32,
// lora_A[16,4096], lora_B[4096,16], sigma[16]. out[4,2048,4096] f32.
// out = x @ (W + SCALING * (B*diag(sigma_masked)) @ A)^T
#define D_DIM 4096
#define R_DIM 16
#define SCALING_F 1.0f          // 16.0/16
#define THRESH 0.01f

typedef __attribute__((ext_vector_type(8))) short short8;   // 8 bf16 = 4 VGPRs
typedef __attribute__((ext_vector_type(4))) float floatx4;  // MFMA C/D

__device__ __forceinline__ unsigned int f2bf(float f) {
  union { float f; unsigned int u; } v; v.f = f;
  unsigned int u = v.u;
  u += 0x7FFFu + ((u >> 16) & 1u);   // round-to-nearest-even
  return u >> 16;
}

// ---------- fused prep: x f32->bf16 AND W_eff build, one launch ----------
__global__ __launch_bounds__(256) void prep_kernel(
    const float* __restrict__ x, unsigned int* __restrict__ xb, int n8,
    int nxblocks,
    const float* __restrict__ W, const float* __restrict__ lA,
    const float* __restrict__ lB, const float* __restrict__ sigma,
    unsigned int* __restrict__ wb) {
  __shared__ float Bs[R_DIM];
  int b = blockIdx.x;
  if (b < nxblocks) {
    int idx = b * 256 + threadIdx.x;
    if (idx >= n8) return;
    const float4* xp = (const float4*)x;
    float4 v0 = xp[2 * idx];
    float4 v1 = xp[2 * idx + 1];
    uint4 o;
    o.x = f2bf(v0.x) | (f2bf(v0.y) << 16);
    o.y = f2bf(v0.z) | (f2bf(v0.w) << 16);
    o.z = f2bf(v1.x) | (f2bf(v1.y) << 16);
    o.w = f2bf(v1.z) | (f2bf(v1.w) << 16);
    ((uint4*)xb)[idx] = o;
  } else {
    int idx = (b - nxblocks) * 256 + threadIdx.x;  // float4 index
    int o  = idx >> 10;                             // row (uniform per block)
    int dq = idx & 1023;
    if (threadIdx.x < R_DIM) {
      float s = sigma[threadIdx.x];
      s = (fabsf(s) >= THRESH) ? s : 0.0f;
      Bs[threadIdx.x] = lB[o * R_DIM + threadIdx.x] * s * SCALING_F;
    }
    __syncthreads();
    float4 acc = ((const float4*)W)[idx];
#pragma unroll
    for (int r = 0; r < R_DIM; ++r) {
      float bb = Bs[r];
      float4 a = ((const float4*)(lA + (size_t)r * D_DIM))[dq];
      acc.x += bb * a.x; acc.y += bb * a.y; acc.z += bb * a.z; acc.w += bb * a.w;
    }
    uint2 p;
    p.x = f2bf(acc.x) | (f2bf(acc.y) << 16);
    p.y = f2bf(acc.z) | (f2bf(acc.w) << 16);
    ((uint2*)wb)[idx] = p;
  }
}

// =====================================================================
// GEMM: C[M,N] = A[M,K] * B[N,K]^T, bf16 in, f32 out.
// 256x256 tile, BK=64, 8 waves (2M x 4N), 512 threads, 128 KiB LDS.
//
// 4-phase/K-tile pipeline, CROSS-PHASE FRAGMENT PREFETCH, ONE barrier/phase:
//   {stage 2 x global_load_lds; vmcnt(8); s_barrier;
//    ds_read NEXT phase's frags; 16 MFMA on PREVIOUS phase's frags}
// NO inline-asm lgkm waits: the compiler's own dependency tracking inserts
// minimal lgkmcnt before each MFMA (its counts are fine-grained; asm waits
// with "memory" clobbers were observed to force conservative lgkmcnt(0),
// re-serializing LDS drain and MFMA — R1/R2 both measured 50% MfmaUtil).
// sched_barrier(0) only around the vmcnt+barrier publication cluster.
//
// LDS map (bytes): A-buf0 @0, A-buf1 @32768, B-buf0 @65536, B-buf1 @98304.
// Tile = 256 rows x 64 bf16 = 32 KB, row stride 128 B. Row permutation:
//   A: LDS row = qm*128 + wm*64 + i ; B: LDS row = qn*128 + wn*32 + i
// 16B-granule XOR swizzle: slot s holds kgroup s^(row&7); inverse applied
// to GLOBAL source addr (linear LDS dest), same XOR on ds_read. 0 conflicts.
//
// Quadrant order per tile t: c1=(0,0) c2=(0,1) c3=(1,1) c4=(1,0).
// Frag register buffers: afX=A0, afY=A1, bf0A/bf0B=B0 (tile parity), bf1=B1.
// Staging rotation (2 loads/phase), distance 4 from its consuming read:
//   4t: B1(t+1) | 4t+1: A1(t+1) | 4t+2: A0(t+2) | 4t+3: B0(t+2)
// vmcnt(8) at phase top drains loads from 4 phases ago; the s_barrier then
// publishes them CU-wide. All concurrent stage-vs-read region pairs across
// the 8-phase frame verified disjoint. Tail stages wrap &8191 (harmless).
// =====================================================================

__device__ __forceinline__ void stage16(const void* g, void* l) {
  __builtin_amdgcn_global_load_lds(
      (const __attribute__((address_space(1))) void*)g,
      (__attribute__((address_space(3))) void*)l, 16, 0, 0);
}

#define FENCE() __builtin_amdgcn_sched_barrier(0)

#define WAIT_VM8_BAR()                                  \
  FENCE();                                              \
  asm volatile("s_waitcnt vmcnt(8)" ::: "memory");      \
  __builtin_amdgcn_s_barrier();                         \
  FENCE()

#define LOADA_TO(DST, BUF, QM)                                                 \
  _Pragma("unroll") for (int t = 0; t < 4; ++t) {                              \
    DST[t][0] = *(const short8*)(aRd0 + (BUF)*32768 + (QM)*16384 + t*2048);    \
    DST[t][1] = *(const short8*)(aRd1 + (BUF)*32768 + (QM)*16384 + t*2048);    \
  }

#define LOADB_TO(DST, BUF, QN)                                                 \
  _Pragma("unroll") for (int j = 0; j < 2; ++j) {                              \
    DST[j][0] = *(const short8*)(bRd0 + (BUF)*32768 + (QN)*16384 + j*2048);    \
    DST[j][1] = *(const short8*)(bRd1 + (BUF)*32768 + (QN)*16384 + j*2048);    \
  }

#define MFMA16(QM, QN, AF, BF)                                                 \
  __builtin_amdgcn_s_setprio(1);                                               \
  _Pragma("unroll") for (int t = 0; t < 4; ++t)                                \
  _Pragma("unroll") for (int j = 0; j < 2; ++j)                                \
    acc[QM][QN][t][j] = __builtin_amdgcn_mfma_f32_16x16x32_bf16(               \
        AF[t][0], BF[j][0], acc[QM][QN][t][j], 0, 0, 0);                       \
  _Pragma("unroll") for (int t = 0; t < 4; ++t)                                \
  _Pragma("unroll") for (int j = 0; j < 2; ++j)                                \
    acc[QM][QN][t][j] = __builtin_amdgcn_mfma_f32_16x16x32_bf16(               \
        AF[t][1], BF[j][1], acc[QM][QN][t][j], 0, 0, 0);                       \
  __builtin_amdgcn_s_setprio(0);

__global__ __launch_bounds__(512, 2) void gemm_bt_kernel(
    const unsigned short* __restrict__ A,   // x bf16 [M, K]
    const unsigned short* __restrict__ B,   // W_eff bf16 [N, K]
    float* __restrict__ C, int M) {
  __shared__ __align__(16) char lds[131072];

  const int tid  = threadIdx.x;
  const int lane = tid & 63;
  const int wave = tid >> 6;      // 0..7
  const int wm   = wave >> 2;     // 0..1 (128 rows each)
  const int wn   = wave & 3;      // 0..3 (64 cols each)
  const int lrow = lane & 15;
  const int lq   = lane >> 4;     // 0..3
  const int r7   = lrow & 7;

  // XCD-bijective block swizzle (gridDim.x % 8 == 0 here: 512 blocks).
  const int bid = blockIdx.x;
  const int cpx = gridDim.x >> 3;
  const int swz = (bid & 7) * cpx + (bid >> 3);
  const int m0 = (swz >> 4) << 8;           // 16 n-tiles (D_DIM/256)
  const int n0 = (swz & 15) << 8;

  // ---- staging source bases (per thread) ----
  const int rr8  = tid >> 3;                               // 0..63
  const int kgsw = (tid & 7) ^ (rr8 & 7);
  const char* aSrc = (const char*)A + ((size_t)(m0 + rr8) << 13) + (kgsw << 4);
  const int nrow = (rr8 & 31) | ((rr8 & 32) << 1);
  const char* bSrc = (const char*)B + ((size_t)(n0 + nrow) << 13) + (kgsw << 4);
  char* ldsW = lds + wave * 1024;           // wave-uniform dest base

  // ---- fragment read bases (per lane) ----
  const char* aRd0 = lds + wm * 8192 + lrow * 128 + ((lq ^ r7) << 4);
  const char* aRd1 = lds + wm * 8192 + lrow * 128 + (((4 | lq) ^ r7) << 4);
  const char* bRd0 = lds + 65536 + wn * 4096 + lrow * 128 + ((lq ^ r7) << 4);
  const char* bRd1 = lds + 65536 + wn * 4096 + lrow * 128 + (((4 | lq) ^ r7) << 4);

  short8 afX[4][2], afY[4][2];          // A0 / A1 fragments
  short8 bf0A[2][2], bf0B[2][2];        // B0 fragments (tile parity)
  short8 bf1[2][2];                     // B1 fragments
  floatx4 acc[2][2][4][2] = {};         // [qm][qn][t][j]

  // ---- prologue: stage order fixes the distance-4/vmcnt(8) invariant ----
  stage16(aSrc,                      ldsW + 0);        // A0(0)
  stage16(aSrc + (128 << 13),        ldsW + 8192);
  stage16(bSrc,                      ldsW + 65536);    // B0(0)
  stage16(bSrc + (128 << 13),        ldsW + 73728);
  stage16(bSrc + (32 << 13),         ldsW + 81920);    // B1(0)
  stage16(bSrc + (160 << 13),        ldsW + 90112);
  stage16(aSrc + (64 << 13),         ldsW + 16384);    // A1(0)
  stage16(aSrc + (192 << 13),        ldsW + 24576);
  stage16(aSrc + 128,                ldsW + 32768);    // A0(1) -> buf1
  stage16(aSrc + (128 << 13) + 128,  ldsW + 40960);
  stage16(bSrc + 128,                ldsW + 98304);    // B0(1) -> buf1
  stage16(bSrc + (128 << 13) + 128,  ldsW + 106496);
  FENCE();
  asm volatile("s_waitcnt vmcnt(8)" ::: "memory");     // A0(0),B0(0) landed
  __builtin_amdgcn_s_barrier();
  FENCE();
  LOADA_TO(afX, 0, 0)                                  // A0(0)
  LOADB_TO(bf0A, 0, 0)                                 // B0(0)

  int kb = 0;
#pragma unroll 1
  for (int f = 0; f < 32; ++f) {             // 64 K-tiles, 2 per frame
    const int k1 = (kb + 128) & 8191;        // tile 2f+1
    const int k2 = (kb + 256) & 8191;        // tile 2f+2 (wraps at tail)
    const int k3 = (kb + 384) & 8191;        // tile 2f+3 (wraps at tail)

    // p0: c1(e)=A0*B0 | stage B1(o)->buf1 | read bf1 <- B1(e) buf0
    stage16(bSrc + (32 << 13) + k1,  ldsW + 114688);
    stage16(bSrc + (160 << 13) + k1, ldsW + 122880);
    WAIT_VM8_BAR();
    LOADB_TO(bf1, 0, 1)
    MFMA16(0, 0, afX, bf0A);

    // p1: c2(e)=A0*B1 | stage A1(o)->buf1 | read afY <- A1(e) buf0
    stage16(aSrc + (64 << 13) + k1,  ldsW + 49152);
    stage16(aSrc + (192 << 13) + k1, ldsW + 57344);
    WAIT_VM8_BAR();
    LOADA_TO(afY, 0, 1)
    MFMA16(0, 1, afX, bf1);

    // p2: c3(e)=A1*B1 | stage A0(2f+2)->buf0 | read afX <- A0(o) buf1
    stage16(aSrc + k2,               ldsW + 0);
    stage16(aSrc + (128 << 13) + k2, ldsW + 8192);
    WAIT_VM8_BAR();
    LOADA_TO(afX, 1, 0)
    MFMA16(1, 1, afY, bf1);

    // p3: c4(e)=A1*B0 | stage B0(2f+2)->buf0 | read bf0B <- B0(o) buf1
    stage16(bSrc + k2,               ldsW + 65536);
    stage16(bSrc + (128 << 13) + k2, ldsW + 73728);
    WAIT_VM8_BAR();
    LOADB_TO(bf0B, 1, 0)
    MFMA16(1, 0, afY, bf0A);

    // p4: c1(o)=A0*B0 | stage B1(2f+2)->buf0 | read bf1 <- B1(o) buf1
    stage16(bSrc + (32 << 13) + k2,  ldsW + 81920);
    stage16(bSrc + (160 << 13) + k2, ldsW + 90112);
    WAIT_VM8_BAR();
    LOADB_TO(bf1, 1, 1)
    MFMA16(0, 0, afX, bf0B);

    // p5: c2(o)=A0*B1 | stage A1(2f+2)->buf0 | read afY <- A1(o) buf1
    stage16(aSrc + (64 << 13) + k2,  ldsW + 16384);
    stage16(aSrc + (192 << 13) + k2, ldsW + 24576);
    WAIT_VM8_BAR();
    LOADA_TO(afY, 1, 1)
    MFMA16(0, 1, afX, bf1);

    // p6: c3(o)=A1*B1 | stage A0(2f+3)->buf1 | read afX <- A0(2f+2) buf0
    stage16(aSrc + k3,               ldsW + 32768);
    stage16(aSrc + (128 << 13) + k3, ldsW + 40960);
    WAIT_VM8_BAR();
    LOADA_TO(afX, 0, 0)
    MFMA16(1, 1, afY, bf1);

    // p7: c4(o)=A1*B0 | stage B0(2f+3)->buf1 | read bf0A <- B0(2f+2) buf0
    stage16(bSrc + k3,               ldsW + 98304);
    stage16(bSrc + (128 << 13) + k3, ldsW + 106496);
    WAIT_VM8_BAR();
    LOADB_TO(bf0A, 0, 0)
    MFMA16(1, 0, afY, bf0B);

    kb += 256;
  }

  // ---- epilogue: D row=(lq*4+rr), col=lrow within each 16x16 fragment ----
#pragma unroll
  for (int qm = 0; qm < 2; ++qm)
#pragma unroll
    for (int t = 0; t < 4; ++t)
#pragma unroll
      for (int rr = 0; rr < 4; ++rr) {
        float* cp = C +
            (size_t)(m0 + wm * 128 + qm * 64 + t * 16 + lq * 4 + rr) * D_DIM +
            n0 + wn * 64 + lrow;
#pragma unroll
        for (int qn = 0; qn < 2; ++qn)
#pragma unroll
          for (int j = 0; j < 2; ++j)
            cp[qn * 32 + j * 16] = acc[qm][qn][t][j][rr];
      }
}

extern "C" void kernel_launch(void* const* d_in, const int* in_sizes, int n_in,
                              void* d_out, int out_size, void* d_ws, size_t ws_size,
                              hipStream_t stream) {
  const float* x     = (const float*)d_in[0];  // [M, 4096], M = 8192
  const float* W     = (const float*)d_in[1];  // [4096, 4096]
  const float* lA    = (const float*)d_in[2];  // [16, 4096]
  const float* lB    = (const float*)d_in[3];  // [4096, 16]
  const float* sigma = (const float*)d_in[4];  // [16]
  float* out = (float*)d_out;

  const int M = in_sizes[0] / D_DIM;           // 8192
  // Workspace layout: x_bf16 (M*4096*2 = 64 MB) then W_eff bf16 (32 MB).
  unsigned int* xb = (unsigned int*)d_ws;
  unsigned int* wb = (unsigned int*)((char*)d_ws + (size_t)M * D_DIM * 2);

  const int n8 = in_sizes[0] / 8;              // x octets
  const int nxblocks = (n8 + 255) / 256;       // 16384
  const int nwblocks = (D_DIM * D_DIM / 4) / 256;  // 16384
  prep_kernel<<<nxblocks + nwblocks, 256, 0, stream>>>(
      x, xb, n8, nxblocks, W, lA, lB, sigma, wb);

  const int nblocks = (M / 256) * (D_DIM / 256);   // 32*16 = 512
  gemm_bt_kernel<<<nblocks, 512, 0, stream>>>(
      (const unsigned short*)xb, (const unsigned short*)wb, out, M);
}

// Round 6
// 503.837 us; speedup vs baseline: 1.0965x; 1.0570x over previous
//
#include <hip/hip_runtime.h>

// Problem dims (fixed by setup_inputs): x[4,2048,4096] f32, W[4096,4096] f32,
// lora_A[16,4096], lora_B[4096,16], sigma[16]. out[4,2048,4096] f32.
// out = x @ (W + SCALING * (B*diag(sigma_masked)) @ A)^T
#define D_DIM 4096
#define R_DIM 16
#define SCALING_F 1.0f          // 16.0/16
#define THRESH 0.01f

typedef __attribute__((ext_vector_type(8))) short short8;   // 8 bf16 = 4 VGPRs
typedef __attribute__((ext_vector_type(4))) float floatx4;  // MFMA C/D

__device__ __forceinline__ unsigned int f2bf(float f) {
  union { float f; unsigned int u; } v; v.f = f;
  unsigned int u = v.u;
  u += 0x7FFFu + ((u >> 16) & 1u);   // round-to-nearest-even
  return u >> 16;
}

// ---------- fused prep: x f32->bf16 AND W_eff build, one launch ----------
__global__ __launch_bounds__(256) void prep_kernel(
    const float* __restrict__ x, unsigned int* __restrict__ xb, int n8,
    int nxblocks,
    const float* __restrict__ W, const float* __restrict__ lA,
    const float* __restrict__ lB, const float* __restrict__ sigma,
    unsigned int* __restrict__ wb) {
  __shared__ float Bs[R_DIM];
  int b = blockIdx.x;
  if (b < nxblocks) {
    int idx = b * 256 + threadIdx.x;
    if (idx >= n8) return;
    const float4* xp = (const float4*)x;
    float4 v0 = xp[2 * idx];
    float4 v1 = xp[2 * idx + 1];
    uint4 o;
    o.x = f2bf(v0.x) | (f2bf(v0.y) << 16);
    o.y = f2bf(v0.z) | (f2bf(v0.w) << 16);
    o.z = f2bf(v1.x) | (f2bf(v1.y) << 16);
    o.w = f2bf(v1.z) | (f2bf(v1.w) << 16);
    ((uint4*)xb)[idx] = o;
  } else {
    int idx = (b - nxblocks) * 256 + threadIdx.x;  // float4 index
    int o  = idx >> 10;                             // row (uniform per block)
    int dq = idx & 1023;
    if (threadIdx.x < R_DIM) {
      float s = sigma[threadIdx.x];
      s = (fabsf(s) >= THRESH) ? s : 0.0f;
      Bs[threadIdx.x] = lB[o * R_DIM + threadIdx.x] * s * SCALING_F;
    }
    __syncthreads();
    float4 acc = ((const float4*)W)[idx];
#pragma unroll
    for (int r = 0; r < R_DIM; ++r) {
      float bb = Bs[r];
      float4 a = ((const float4*)(lA + (size_t)r * D_DIM))[dq];
      acc.x += bb * a.x; acc.y += bb * a.y; acc.z += bb * a.z; acc.w += bb * a.w;
    }
    uint2 p;
    p.x = f2bf(acc.x) | (f2bf(acc.y) << 16);
    p.y = f2bf(acc.z) | (f2bf(acc.w) << 16);
    ((uint2*)wb)[idx] = p;
  }
}

// =====================================================================
// GEMM: C[M,N] = A[M,K] * B[N,K]^T, bf16 in, f32 out.
// 256x256 tile, BK=64, 8 waves (2M x 4N), 512 threads, 128 KiB LDS.
//
// 4-phase/K-tile pipeline, register-double-buffered fragments, ONE
// barrier/phase. This round (resubmit; R5 was an infra failure):
// sched_group_barrier forces the emitted order inside each phase to
// alternate {1 ds_read, 2-4 MFMA} so the LDS datapath drains DURING the
// MFMA burst (measured: phase = LDS + MFMA fully serial = 1169 cyc across
// R1/R2/R4; MFMA alone = 621 cyc).
// Masks: 0x8 = MFMA, 0x100 = DS_READ (LLVM SchedGroupMask, per m137).
//
// LDS map (bytes): A-buf0 @0, A-buf1 @32768, B-buf0 @65536, B-buf1 @98304.
// Tile = 256 rows x 64 bf16 = 32 KB, row stride 128 B. Row permutation:
//   A: LDS row = qm*128 + wm*64 + i ; B: LDS row = qn*128 + wn*32 + i
// 16B-granule XOR swizzle: slot s holds kgroup s^(row&7); inverse applied
// to GLOBAL source addr (linear LDS dest), same XOR on ds_read. 0 conflicts.
//
// Quadrant order per tile t: c1=(0,0) c2=(0,1) c3=(1,1) c4=(1,0).
// Frag register buffers: afX=A0, afY=A1, bf0A/bf0B=B0 (tile parity), bf1=B1.
// Staging rotation (2 loads/phase), distance 4 from its consuming read:
//   4t: B1(t+1) | 4t+1: A1(t+1) | 4t+2: A0(t+2) | 4t+3: B0(t+2)
// vmcnt(8) at phase top drains loads from 4 phases ago; the s_barrier then
// publishes them CU-wide. All concurrent stage-vs-read region pairs across
// the 8-phase frame verified disjoint. Tail stages wrap &8191 (harmless).
// sched_barrier(0) fences keep the 2-stages-per-phase vmcnt bookkeeping
// exact (stages cannot migrate across phase boundaries).
// =====================================================================

__device__ __forceinline__ void stage16(const void* g, void* l) {
  __builtin_amdgcn_global_load_lds(
      (const __attribute__((address_space(1))) void*)g,
      (__attribute__((address_space(3))) void*)l, 16, 0, 0);
}

#define FENCE() __builtin_amdgcn_sched_barrier(0)

#define WAIT_VM8_BAR()                                  \
  FENCE();                                              \
  asm volatile("s_waitcnt vmcnt(8)" ::: "memory");      \
  __builtin_amdgcn_s_barrier();                         \
  FENCE()

// Interleave patterns for the fenced {ds_read + MFMA} region.
__device__ __forceinline__ void sgb_8reads() {   // 8 DS_READ + 16 MFMA
#pragma unroll
  for (int i = 0; i < 8; ++i) {
    __builtin_amdgcn_sched_group_barrier(0x100, 1, 0);
    __builtin_amdgcn_sched_group_barrier(0x008, 2, 0);
  }
}
__device__ __forceinline__ void sgb_4reads() {   // 4 DS_READ + 16 MFMA
#pragma unroll
  for (int i = 0; i < 4; ++i) {
    __builtin_amdgcn_sched_group_barrier(0x100, 1, 0);
    __builtin_amdgcn_sched_group_barrier(0x008, 4, 0);
  }
}

#define LOADA_TO(DST, BUF, QM)                                                 \
  _Pragma("unroll") for (int t = 0; t < 4; ++t) {                              \
    DST[t][0] = *(const short8*)(aRd0 + (BUF)*32768 + (QM)*16384 + t*2048);    \
    DST[t][1] = *(const short8*)(aRd1 + (BUF)*32768 + (QM)*16384 + t*2048);    \
  }

#define LOADB_TO(DST, BUF, QN)                                                 \
  _Pragma("unroll") for (int j = 0; j < 2; ++j) {                              \
    DST[j][0] = *(const short8*)(bRd0 + (BUF)*32768 + (QN)*16384 + j*2048);    \
    DST[j][1] = *(const short8*)(bRd1 + (BUF)*32768 + (QN)*16384 + j*2048);    \
  }

#define MFMA16(QM, QN, AF, BF)                                                 \
  _Pragma("unroll") for (int t = 0; t < 4; ++t)                                \
  _Pragma("unroll") for (int j = 0; j < 2; ++j)                                \
    acc[QM][QN][t][j] = __builtin_amdgcn_mfma_f32_16x16x32_bf16(               \
        AF[t][0], BF[j][0], acc[QM][QN][t][j], 0, 0, 0);                       \
  _Pragma("unroll") for (int t = 0; t < 4; ++t)                                \
  _Pragma("unroll") for (int j = 0; j < 2; ++j)                                \
    acc[QM][QN][t][j] = __builtin_amdgcn_mfma_f32_16x16x32_bf16(               \
        AF[t][1], BF[j][1], acc[QM][QN][t][j], 0, 0, 0);

__global__ __launch_bounds__(512, 2) void gemm_bt_kernel(
    const unsigned short* __restrict__ A,   // x bf16 [M, K]
    const unsigned short* __restrict__ B,   // W_eff bf16 [N, K]
    float* __restrict__ C, int M) {
  __shared__ __align__(16) char lds[131072];

  const int tid  = threadIdx.x;
  const int lane = tid & 63;
  const int wave = tid >> 6;      // 0..7
  const int wm   = wave >> 2;     // 0..1 (128 rows each)
  const int wn   = wave & 3;      // 0..3 (64 cols each)
  const int lrow = lane & 15;
  const int lq   = lane >> 4;     // 0..3
  const int r7   = lrow & 7;

  // XCD-bijective block swizzle (gridDim.x % 8 == 0 here: 512 blocks).
  const int bid = blockIdx.x;
  const int cpx = gridDim.x >> 3;
  const int swz = (bid & 7) * cpx + (bid >> 3);
  const int m0 = (swz >> 4) << 8;           // 16 n-tiles (D_DIM/256)
  const int n0 = (swz & 15) << 8;

  // ---- staging source bases (per thread) ----
  const int rr8  = tid >> 3;                               // 0..63
  const int kgsw = (tid & 7) ^ (rr8 & 7);
  const char* aSrc = (const char*)A + ((size_t)(m0 + rr8) << 13) + (kgsw << 4);
  const int nrow = (rr8 & 31) | ((rr8 & 32) << 1);
  const char* bSrc = (const char*)B + ((size_t)(n0 + nrow) << 13) + (kgsw << 4);
  char* ldsW = lds + wave * 1024;           // wave-uniform dest base

  // ---- fragment read bases (per lane) ----
  const char* aRd0 = lds + wm * 8192 + lrow * 128 + ((lq ^ r7) << 4);
  const char* aRd1 = lds + wm * 8192 + lrow * 128 + (((4 | lq) ^ r7) << 4);
  const char* bRd0 = lds + 65536 + wn * 4096 + lrow * 128 + ((lq ^ r7) << 4);
  const char* bRd1 = lds + 65536 + wn * 4096 + lrow * 128 + (((4 | lq) ^ r7) << 4);

  short8 afX[4][2], afY[4][2];          // A0 / A1 fragments
  short8 bf0A[2][2], bf0B[2][2];        // B0 fragments (tile parity)
  short8 bf1[2][2];                     // B1 fragments
  floatx4 acc[2][2][4][2] = {};         // [qm][qn][t][j]

  // ---- prologue: stage order fixes the distance-4/vmcnt(8) invariant ----
  stage16(aSrc,                      ldsW + 0);        // A0(0)
  stage16(aSrc + (128 << 13),        ldsW + 8192);
  stage16(bSrc,                      ldsW + 65536);    // B0(0)
  stage16(bSrc + (128 << 13),        ldsW + 73728);
  stage16(bSrc + (32 << 13),         ldsW + 81920);    // B1(0)
  stage16(bSrc + (160 << 13),        ldsW + 90112);
  stage16(aSrc + (64 << 13),         ldsW + 16384);    // A1(0)
  stage16(aSrc + (192 << 13),        ldsW + 24576);
  stage16(aSrc + 128,                ldsW + 32768);    // A0(1) -> buf1
  stage16(aSrc + (128 << 13) + 128,  ldsW + 40960);
  stage16(bSrc + 128,                ldsW + 98304);    // B0(1) -> buf1
  stage16(bSrc + (128 << 13) + 128,  ldsW + 106496);
  FENCE();
  asm volatile("s_waitcnt vmcnt(8)" ::: "memory");     // A0(0),B0(0) landed
  __builtin_amdgcn_s_barrier();
  FENCE();
  LOADA_TO(afX, 0, 0)                                  // A0(0)
  LOADB_TO(bf0A, 0, 0)                                 // B0(0)
  FENCE();

  int kb = 0;
#pragma unroll 1
  for (int f = 0; f < 32; ++f) {             // 64 K-tiles, 2 per frame
    const int k1 = (kb + 128) & 8191;        // tile 2f+1
    const int k2 = (kb + 256) & 8191;        // tile 2f+2 (wraps at tail)
    const int k3 = (kb + 384) & 8191;        // tile 2f+3 (wraps at tail)

    // p0: c1(e)=A0*B0 | stage B1(o)->buf1 | read bf1 <- B1(e) buf0
    stage16(bSrc + (32 << 13) + k1,  ldsW + 114688);
    stage16(bSrc + (160 << 13) + k1, ldsW + 122880);
    WAIT_VM8_BAR();
    __builtin_amdgcn_s_setprio(1);
    LOADB_TO(bf1, 0, 1)
    MFMA16(0, 0, afX, bf0A);
    sgb_4reads();
    __builtin_amdgcn_s_setprio(0);
    FENCE();

    // p1: c2(e)=A0*B1 | stage A1(o)->buf1 | read afY <- A1(e) buf0
    stage16(aSrc + (64 << 13) + k1,  ldsW + 49152);
    stage16(aSrc + (192 << 13) + k1, ldsW + 57344);
    WAIT_VM8_BAR();
    __builtin_amdgcn_s_setprio(1);
    LOADA_TO(afY, 0, 1)
    MFMA16(0, 1, afX, bf1);
    sgb_8reads();
    __builtin_amdgcn_s_setprio(0);
    FENCE();

    // p2: c3(e)=A1*B1 | stage A0(2f+2)->buf0 | read afX <- A0(o) buf1
    stage16(aSrc + k2,               ldsW + 0);
    stage16(aSrc + (128 << 13) + k2, ldsW + 8192);
    WAIT_VM8_BAR();
    __builtin_amdgcn_s_setprio(1);
    LOADA_TO(afX, 1, 0)
    MFMA16(1, 1, afY, bf1);
    sgb_8reads();
    __builtin_amdgcn_s_setprio(0);
    FENCE();

    // p3: c4(e)=A1*B0 | stage B0(2f+2)->buf0 | read bf0B <- B0(o) buf1
    stage16(bSrc + k2,               ldsW + 65536);
    stage16(bSrc + (128 << 13) + k2, ldsW + 73728);
    WAIT_VM8_BAR();
    __builtin_amdgcn_s_setprio(1);
    LOADB_TO(bf0B, 1, 0)
    MFMA16(1, 0, afY, bf0A);
    sgb_4reads();
    __builtin_amdgcn_s_setprio(0);
    FENCE();

    // p4: c1(o)=A0*B0 | stage B1(2f+2)->buf0 | read bf1 <- B1(o) buf1
    stage16(bSrc + (32 << 13) + k2,  ldsW + 81920);
    stage16(bSrc + (160 << 13) + k2, ldsW + 90112);
    WAIT_VM8_BAR();
    __builtin_amdgcn_s_setprio(1);
    LOADB_TO(bf1, 1, 1)
    MFMA16(0, 0, afX, bf0B);
    sgb_4reads();
    __builtin_amdgcn_s_setprio(0);
    FENCE();

    // p5: c2(o)=A0*B1 | stage A1(2f+2)->buf0 | read afY <- A1(o) buf1
    stage16(aSrc + (64 << 13) + k2,  ldsW + 16384);
    stage16(aSrc + (192 << 13) + k2, ldsW + 24576);
    WAIT_VM8_BAR();
    __builtin_amdgcn_s_setprio(1);
    LOADA_TO(afY, 1, 1)
    MFMA16(0, 1, afX, bf1);
    sgb_8reads();
    __builtin_amdgcn_s_setprio(0);
    FENCE();

    // p6: c3(o)=A1*B1 | stage A0(2f+3)->buf1 | read afX <- A0(2f+2) buf0
    stage16(aSrc + k3,               ldsW + 32768);
    stage16(aSrc + (128 << 13) + k3, ldsW + 40960);
    WAIT_VM8_BAR();
    __builtin_amdgcn_s_setprio(1);
    LOADA_TO(afX, 0, 0)
    MFMA16(1, 1, afY, bf1);
    sgb_8reads();
    __builtin_amdgcn_s_setprio(0);
    FENCE();

    // p7: c4(o)=A1*B0 | stage B0(2f+3)->buf1 | read bf0A <- B0(2f+2) buf0
    stage16(bSrc + k3,               ldsW + 98304);
    stage16(bSrc + (128 << 13) + k3, ldsW + 106496);
    WAIT_VM8_BAR();
    __builtin_amdgcn_s_setprio(1);
    LOADB_TO(bf0A, 0, 0)
    MFMA16(1, 0, afY, bf0B);
    sgb_4reads();
    __builtin_amdgcn_s_setprio(0);
    FENCE();

    kb += 256;
  }

  // ---- epilogue: D row=(lq*4+rr), col=lrow within each 16x16 fragment ----
#pragma unroll
  for (int qm = 0; qm < 2; ++qm)
#pragma unroll
    for (int t = 0; t < 4; ++t)
#pragma unroll
      for (int rr = 0; rr < 4; ++rr) {
        float* cp = C +
            (size_t)(m0 + wm * 128 + qm * 64 + t * 16 + lq * 4 + rr) * D_DIM +
            n0 + wn * 64 + lrow;
#pragma unroll
        for (int qn = 0; qn < 2; ++qn)
#pragma unroll
          for (int j = 0; j < 2; ++j)
            cp[qn * 32 + j * 16] = acc[qm][qn][t][j][rr];
      }
}

extern "C" void kernel_launch(void* const* d_in, const int* in_sizes, int n_in,
                              void* d_out, int out_size, void* d_ws, size_t ws_size,
                              hipStream_t stream) {
  const float* x     = (const float*)d_in[0];  // [M, 4096], M = 8192
  const float* W     = (const float*)d_in[1];  // [4096, 4096]
  const float* lA    = (const float*)d_in[2];  // [16, 4096]
  const float* lB    = (const float*)d_in[3];  // [4096, 16]
  const float* sigma = (const float*)d_in[4];  // [16]
  float* out = (float*)d_out;

  const int M = in_sizes[0] / D_DIM;           // 8192
  // Workspace layout: x_bf16 (M*4096*2 = 64 MB) then W_eff bf16 (32 MB).
  unsigned int* xb = (unsigned int*)d_ws;
  unsigned int* wb = (unsigned int*)((char*)d_ws + (size_t)M * D_DIM * 2);

  const int n8 = in_sizes[0] / 8;              // x octets
  const int nxblocks = (n8 + 255) / 256;       // 16384
  const int nwblocks = (D_DIM * D_DIM / 4) / 256;  // 16384
  prep_kernel<<<nxblocks + nwblocks, 256, 0, stream>>>(
      x, xb, n8, nxblocks, W, lA, lB, sigma, wb);

  const int nblocks = (M / 256) * (D_DIM / 256);   // 32*16 = 512
  gemm_bt_kernel<<<nblocks, 512, 0, stream>>>(
      (const unsigned short*)xb, (const unsigned short*)wb, out, M);
}